// Round 9
// baseline (116.477 us; speedup 1.0000x reference)
//
#include <hip/hip_runtime.h>
#include <hip/hip_bf16.h>
#include <math.h>

#define B_ 8
#define N_ 256
#define H_ 128
#define NODES_ (B_ * N_)   // 2048

__device__ __forceinline__ float silu_fast(float x) {
    float e = __expf(-x);
    return x * __builtin_amdgcn_rcpf(1.0f + e);
}

// ---------------------------------------------------------------------------
// k1 (split-K): g=0: P = node@We1a + be1
//               g=1: Q = node@We1b + (m_j-1)*1e30   (mask_j folded: silu -> -0)
//               g=2: pre = node@Wn1a + bn1
// grid 1536 = 3 gemms x 512 tiles (4 nodes), block 512.
// Each weight float4 loaded by exactly one thread (no L2 amplification),
// reused across 4 nodes; 16-way k-segment reduce through LDS.  [R8: proven]
// ---------------------------------------------------------------------------
__global__ __launch_bounds__(512) void k1(
    const float* __restrict__ node, const float* __restrict__ We1,
    const float* __restrict__ be1, const float* __restrict__ Wn1,
    const float* __restrict__ bn1, const float* __restrict__ mask,
    float* __restrict__ P, float* __restrict__ Q, float* __restrict__ pre)
{
    __shared__ __align__(16) float act[4][128];
    __shared__ __align__(16) float pls[16][4][128];
    const int t = threadIdx.x;
    const int g = blockIdx.x >> 9;
    const int node0 = (blockIdx.x & 511) * 4;

    if (t < 128) {
        int r = t >> 5, col = (t & 31) * 4;
        *(float4*)(&act[r][col]) = *(const float4*)(node + (size_t)(node0 + r) * H_ + col);
    }
    const float* W = (g == 0) ? We1 : (g == 1) ? (We1 + 128 * H_) : Wn1;
    const int kseg = t >> 5;
    const int c0   = (t & 31) * 4;
    __syncthreads();

    float4 w[8];
    const float* Wb = W + (size_t)(kseg * 8) * H_ + c0;
    #pragma unroll
    for (int u = 0; u < 8; ++u) w[u] = *(const float4*)(Wb + u * H_);

    #pragma unroll
    for (int n = 0; n < 4; ++n) {
        float4 a = {0.f, 0.f, 0.f, 0.f};
        #pragma unroll
        for (int u = 0; u < 8; ++u) {
            float v = act[n][kseg * 8 + u];
            a.x = fmaf(v, w[u].x, a.x);
            a.y = fmaf(v, w[u].y, a.y);
            a.z = fmaf(v, w[u].z, a.z);
            a.w = fmaf(v, w[u].w, a.w);
        }
        *(float4*)(&pls[kseg][n][c0]) = a;
    }
    __syncthreads();

    {
        const int n = t >> 7;
        const int c = t & 127;
        float s = 0.f;
        #pragma unroll
        for (int seg = 0; seg < 16; ++seg) s += pls[seg][n][c];
        float* op;
        if (g == 0)      { op = P;   s += be1[c]; }
        else if (g == 1) { op = Q;   s += (mask[node0 + n] - 1.0f) * 1e30f; }
        else             { op = pre; s += bn1[c]; }
        op[(size_t)(node0 + n) * H_ + c] = s;
    }
}

// ---------------------------------------------------------------------------
// k2bc (R9): fused edge loop + node epilogue. grid 512 (4 i/block), block 256.
// Edge: thread = (g = t>>7 -> i pair {i0+2g, i0+2g+1}, c = t&127); each q LDS
// read shared across 2 i-accumulators; d read as BROADCAST float4 from
// transposed dt[i][j] (4 j per instruction) -> ~5.8 issue slots per eval
// (was ~11 with 1 i/thread + per-j b32 d reads).
// Epilogue: 3 chained split-K GEMMs (8 ksegs x 16 k, two 8-k halves to cap
// VGPR), S'/T/hidden live in LDS.
// ---------------------------------------------------------------------------
__global__ __launch_bounds__(256) void k2bc(
    const float* __restrict__ P, const float* __restrict__ Q,
    const float* __restrict__ We1, const float* __restrict__ positions,
    const float* __restrict__ mask, const float* __restrict__ pre,
    const float* __restrict__ node,
    const float* __restrict__ We2, const float* __restrict__ be2,
    const float* __restrict__ Wn1, const float* __restrict__ Wn2,
    const float* __restrict__ bn2, float* __restrict__ out)
{
    __shared__ __align__(16) float arena[8192];   // 32 KB: Qs chunk | pls[8][4][128]
    __shared__ __align__(16) float dt[4][260];    // transposed dist [i][j], pad 4
    __shared__ float Sls[4][128];
    __shared__ float Tls[4][128];
    __shared__ float cs;
    const int t  = threadIdx.x;
    const int b  = blockIdx.x >> 6;
    const int i0 = (blockIdx.x & 63) * 4;

    // distances: thread owns j = t, fills all 4 i-rows (transposed layout)
    {
        const float* pb = positions + b * N_ * 3;
        const float pjx = pb[t * 3 + 0];
        const float pjy = pb[t * 3 + 1];
        const float pjz = pb[t * 3 + 2];
        #pragma unroll
        for (int il = 0; il < 4; ++il) {
            float dx = pb[(i0 + il) * 3 + 0] - pjx;   // i-coords: uniform loads
            float dy = pb[(i0 + il) * 3 + 1] - pjy;
            float dz = pb[(i0 + il) * 3 + 2] - pjz;
            float sq = dx * dx + dy * dy + dz * dz;
            dt[il][t] = (sq > 0.f) ? sqrtf(sq) : 0.f;
        }
    }
    if (t < 64) {   // cnt = sum_j mask[b][j]
        float mv = mask[b * N_ + t] + mask[b * N_ + 64 + t]
                 + mask[b * N_ + 128 + t] + mask[b * N_ + 192 + t];
        #pragma unroll
        for (int off = 32; off >= 1; off >>= 1) mv += __shfl_down(mv, off);
        if (t == 0) cs = mv;
    }

    const int g = t >> 7;             // wave-uniform (0 or 1)
    const int c = t & 127;
    const int iA = i0 + 2 * g;
    const float wd    = We1[256 * H_ + c];
    const float baseA = P[(size_t)(b * N_ + iA)     * H_ + c];
    const float baseB = P[(size_t)(b * N_ + iA + 1) * H_ + c];
    const float4* __restrict__ Qg = (const float4*)(Q + (size_t)(b * N_) * H_);

    // prefetch chunk 0: 64 j x 128 c = 32 KB; 256 threads x 8 float4
    float4 r[8];
    #pragma unroll
    for (int u = 0; u < 8; ++u) r[u] = Qg[u * 256 + t];

    float accA = 0.f, accB = 0.f;
    for (int ch = 0; ch < 4; ++ch) {
        __syncthreads();              // previous chunk's compute done
        #pragma unroll
        for (int u = 0; u < 8; ++u) ((float4*)arena)[u * 256 + t] = r[u];
        if (ch < 3) {
            #pragma unroll
            for (int u = 0; u < 8; ++u) r[u] = Qg[(ch + 1) * 2048 + u * 256 + t];
        }
        __syncthreads();              // staging visible
        const int j0 = ch * 64;
        #pragma unroll 4
        for (int jw = 0; jw < 64; jw += 4) {
            float4 dA = *(const float4*)(&dt[2 * g][j0 + jw]);       // broadcast
            float4 dB = *(const float4*)(&dt[2 * g + 1][j0 + jw]);   // broadcast
            #pragma unroll
            for (int u = 0; u < 4; ++u) {
                float q  = arena[(jw + u) * 128 + c];
                float du0 = (u == 0) ? dA.x : (u == 1) ? dA.y : (u == 2) ? dA.z : dA.w;
                float du1 = (u == 0) ? dB.x : (u == 1) ? dB.y : (u == 2) ? dB.z : dB.w;
                float xA = fmaf(du0, wd, baseA + q);
                float xB = fmaf(du1, wd, baseB + q);
                float eA = __expf(-xA);
                float eB = __expf(-xB);
                float rA = __builtin_amdgcn_rcpf(1.0f + eA);
                float rB = __builtin_amdgcn_rcpf(1.0f + eB);
                accA = fmaf(xA, rA, accA);    // masked j: x~-1e30, r=0 -> +(-0)
                accB = fmaf(xB, rB, accB);
            }
        }
    }

    const float inv_cnt = __builtin_amdgcn_rcpf(fmaxf(cs, 1.0f));
    const float miA = mask[b * N_ + iA];
    const float miB = mask[b * N_ + iA + 1];
    Sls[2 * g][c]     = (miA * inv_cnt) * accA;
    Sls[2 * g + 1][c] = (miB * inv_cnt) * accB;
    __syncthreads();                  // Sls visible; arena free for pls

    // ---- epilogue: split-K GEMMs, 8 ksegs x 16 k (two 8-k halves) ----
    float (*pls)[4][128] = (float (*)[4][128])arena;
    const int kseg = t >> 5;          // 0..7
    const int c0   = (t & 31) * 4;

    // G1: T = S' @ We2 + mi*be2
    {
        float4 a[4] = {{0,0,0,0},{0,0,0,0},{0,0,0,0},{0,0,0,0}};
        #pragma unroll
        for (int h = 0; h < 2; ++h) {
            const float* Wb = We2 + (size_t)(kseg * 16 + h * 8) * H_ + c0;
            float4 w[8];
            #pragma unroll
            for (int u = 0; u < 8; ++u) w[u] = *(const float4*)(Wb + u * H_);
            #pragma unroll
            for (int n = 0; n < 4; ++n) {
                #pragma unroll
                for (int u = 0; u < 8; ++u) {
                    float v = Sls[n][kseg * 16 + h * 8 + u];
                    a[n].x = fmaf(v, w[u].x, a[n].x); a[n].y = fmaf(v, w[u].y, a[n].y);
                    a[n].z = fmaf(v, w[u].z, a[n].z); a[n].w = fmaf(v, w[u].w, a[n].w);
                }
            }
        }
        #pragma unroll
        for (int n = 0; n < 4; ++n) *(float4*)(&pls[kseg][n][c0]) = a[n];
    }
    __syncthreads();
    {
        #pragma unroll
        for (int p = 0; p < 2; ++p) {
            const int n = 2 * g + p;
            float s = 0.f;
            #pragma unroll
            for (int seg = 0; seg < 8; ++seg) s += pls[seg][n][c];
            const float mi = mask[b * N_ + i0 + n];
            Tls[n][c] = fmaf(mi, be2[c], s);
        }
    }
    __syncthreads();

    // G2: hidden = silu(pre + T @ Wn1[128:])
    {
        float4 a[4] = {{0,0,0,0},{0,0,0,0},{0,0,0,0},{0,0,0,0}};
        #pragma unroll
        for (int h = 0; h < 2; ++h) {
            const float* Wb = Wn1 + (size_t)(128 + kseg * 16 + h * 8) * H_ + c0;
            float4 w[8];
            #pragma unroll
            for (int u = 0; u < 8; ++u) w[u] = *(const float4*)(Wb + u * H_);
            #pragma unroll
            for (int n = 0; n < 4; ++n) {
                #pragma unroll
                for (int u = 0; u < 8; ++u) {
                    float v = Tls[n][kseg * 16 + h * 8 + u];
                    a[n].x = fmaf(v, w[u].x, a[n].x); a[n].y = fmaf(v, w[u].y, a[n].y);
                    a[n].z = fmaf(v, w[u].z, a[n].z); a[n].w = fmaf(v, w[u].w, a[n].w);
                }
            }
        }
        #pragma unroll
        for (int n = 0; n < 4; ++n) *(float4*)(&pls[kseg][n][c0]) = a[n];
    }
    __syncthreads();
    {
        #pragma unroll
        for (int p = 0; p < 2; ++p) {
            const int n = 2 * g + p;
            float s = 0.f;
            #pragma unroll
            for (int seg = 0; seg < 8; ++seg) s += pls[seg][n][c];
            Sls[n][c] = silu_fast(pre[(size_t)(b * N_ + i0 + n) * H_ + c] + s);
        }
    }
    __syncthreads();

    // G3: out = node + mi * (hidden @ Wn2 + bn2)
    {
        float4 a[4] = {{0,0,0,0},{0,0,0,0},{0,0,0,0},{0,0,0,0}};
        #pragma unroll
        for (int h = 0; h < 2; ++h) {
            const float* Wb = Wn2 + (size_t)(kseg * 16 + h * 8) * H_ + c0;
            float4 w[8];
            #pragma unroll
            for (int u = 0; u < 8; ++u) w[u] = *(const float4*)(Wb + u * H_);
            #pragma unroll
            for (int n = 0; n < 4; ++n) {
                #pragma unroll
                for (int u = 0; u < 8; ++u) {
                    float v = Sls[n][kseg * 16 + h * 8 + u];
                    a[n].x = fmaf(v, w[u].x, a[n].x); a[n].y = fmaf(v, w[u].y, a[n].y);
                    a[n].z = fmaf(v, w[u].z, a[n].z); a[n].w = fmaf(v, w[u].w, a[n].w);
                }
            }
        }
        #pragma unroll
        for (int n = 0; n < 4; ++n) *(float4*)(&pls[kseg][n][c0]) = a[n];
    }
    __syncthreads();
    {
        #pragma unroll
        for (int p = 0; p < 2; ++p) {
            const int n = 2 * g + p;
            float s = 0.f;
            #pragma unroll
            for (int seg = 0; seg < 8; ++seg) s += pls[seg][n][c];
            const float mi = mask[b * N_ + i0 + n];
            const size_t idx = (size_t)(b * N_ + i0 + n) * H_ + c;
            out[idx] = node[idx] + mi * (s + bn2[c]);
        }
    }
}

extern "C" void kernel_launch(void* const* d_in, const int* in_sizes, int n_in,
                              void* d_out, int out_size, void* d_ws, size_t ws_size,
                              hipStream_t stream)
{
    const float* node      = (const float*)d_in[0];
    const float* positions = (const float*)d_in[1];
    const float* mask      = (const float*)d_in[2];
    const float* We1       = (const float*)d_in[3];
    const float* be1       = (const float*)d_in[4];
    const float* We2       = (const float*)d_in[5];
    const float* be2       = (const float*)d_in[6];
    const float* Wn1       = (const float*)d_in[7];
    const float* bn1       = (const float*)d_in[8];
    const float* Wn2       = (const float*)d_in[9];
    const float* bn2       = (const float*)d_in[10];
    float* out = (float*)d_out;

    const size_t SZ = (size_t)NODES_ * H_;     // 1 MB each
    float* P   = (float*)d_ws;
    float* Q   = P + SZ;
    float* pre = Q + SZ;                       // peak ws = 3 MB

    k1  <<<1536, 512, 0, stream>>>(node, We1, be1, Wn1, bn1, mask, P, Q, pre);
    k2bc<<<512,  256, 0, stream>>>(P, Q, We1, positions, mask, pre, node,
                                   We2, be2, Wn1, Wn2, bn2, out);
}

// Round 10
// 104.300 us; speedup vs baseline: 1.1168x; 1.1168x over previous
//
#include <hip/hip_runtime.h>
#include <hip/hip_bf16.h>
#include <math.h>

#define B_ 8
#define N_ 256
#define H_ 128
#define NODES_ (B_ * N_)   // 2048

__device__ __forceinline__ float silu_fast(float x) {
    float e = __expf(-x);
    return x * __builtin_amdgcn_rcpf(1.0f + e);
}

// ---------------------------------------------------------------------------
// k1 (split-K): g=0: P = node@We1a + be1
//               g=1: Q = node@We1b + (m_j-1)*1e30   (mask_j folded: silu -> -0)
//               g=2: pre = node@Wn1a + bn1
// grid 1536 = 3 gemms x 512 tiles (4 nodes), block 512.
// Each weight float4 loaded by exactly one thread (no L2 read amplification),
// reused across 4 nodes; 16-way k-segment reduce through LDS.  [R8: proven]
// ---------------------------------------------------------------------------
__global__ __launch_bounds__(512) void k1(
    const float* __restrict__ node, const float* __restrict__ We1,
    const float* __restrict__ be1, const float* __restrict__ Wn1,
    const float* __restrict__ bn1, const float* __restrict__ mask,
    float* __restrict__ P, float* __restrict__ Q, float* __restrict__ pre)
{
    __shared__ __align__(16) float act[4][128];
    __shared__ __align__(16) float pls[16][4][128];
    const int t = threadIdx.x;
    const int g = blockIdx.x >> 9;
    const int node0 = (blockIdx.x & 511) * 4;

    if (t < 128) {
        int r = t >> 5, col = (t & 31) * 4;
        *(float4*)(&act[r][col]) = *(const float4*)(node + (size_t)(node0 + r) * H_ + col);
    }
    const float* W = (g == 0) ? We1 : (g == 1) ? (We1 + 128 * H_) : Wn1;
    const int kseg = t >> 5;
    const int c0   = (t & 31) * 4;
    __syncthreads();

    float4 w[8];
    const float* Wb = W + (size_t)(kseg * 8) * H_ + c0;
    #pragma unroll
    for (int u = 0; u < 8; ++u) w[u] = *(const float4*)(Wb + u * H_);

    #pragma unroll
    for (int n = 0; n < 4; ++n) {
        float4 a = {0.f, 0.f, 0.f, 0.f};
        #pragma unroll
        for (int u = 0; u < 8; ++u) {
            float v = act[n][kseg * 8 + u];
            a.x = fmaf(v, w[u].x, a.x);
            a.y = fmaf(v, w[u].y, a.y);
            a.z = fmaf(v, w[u].z, a.z);
            a.w = fmaf(v, w[u].w, a.w);
        }
        *(float4*)(&pls[kseg][n][c0]) = a;
    }
    __syncthreads();

    {
        const int n = t >> 7;
        const int c = t & 127;
        float s = 0.f;
        #pragma unroll
        for (int seg = 0; seg < 16; ++seg) s += pls[seg][n][c];
        float* op;
        if (g == 0)      { op = P;   s += be1[c]; }
        else if (g == 1) { op = Q;   s += (mask[node0 + n] - 1.0f) * 1e30f; }
        else             { op = pre; s += bn1[c]; }
        op[(size_t)(node0 + n) * H_ + c] = s;
    }
}

// ---------------------------------------------------------------------------
// k2bc (R10): fused edge loop + node epilogue. grid 512 (4 i/block),
// block 512, __launch_bounds__(512, 4): VGPR cap 128 (kernel needs ~90) so
// the occupancy heuristic cannot spill (R9: no hint -> cap 84 -> 39 MB of
// scratch stores), and 2 blocks/CU = 16 waves/CU for latency hiding.
// Edge: thread = (i = t>>7, c = t&127), ONE accumulator; Q staged to LDS in
// 64-j chunks (register-prefetched one chunk ahead); distances transposed in
// dt[i][j], read as wave-broadcast float4 (4 j / LDS instr, conflict-free).
// Epilogue: 3 chained split-K GEMMs (16 ksegs x 8 k), S'/T/hidden in LDS.
// ---------------------------------------------------------------------------
__global__ __launch_bounds__(512, 4) void k2bc(
    const float* __restrict__ P, const float* __restrict__ Q,
    const float* __restrict__ We1, const float* __restrict__ positions,
    const float* __restrict__ mask, const float* __restrict__ pre,
    const float* __restrict__ node,
    const float* __restrict__ We2, const float* __restrict__ be2,
    const float* __restrict__ Wn1, const float* __restrict__ Wn2,
    const float* __restrict__ bn2, float* __restrict__ out)
{
    __shared__ __align__(16) float arena[8192];   // 32 KB: Qs chunk | pls[16][4][128]
    __shared__ __align__(16) float dt[4][256];    // transposed dist [i][j]
    __shared__ float Sls[4][128];
    __shared__ float Tls[4][128];
    __shared__ float cs;
    const int t  = threadIdx.x;
    const int b  = blockIdx.x >> 6;
    const int i0 = (blockIdx.x & 63) * 4;

    // distances (transposed): thread (t&255) owns j; halves fill i-pairs
    {
        const int j    = t & 255;
        const int half = t >> 8;           // 0: il 0,1   1: il 2,3
        const float* pb = positions + b * N_ * 3;
        const float pjx = pb[j * 3 + 0];
        const float pjy = pb[j * 3 + 1];
        const float pjz = pb[j * 3 + 2];
        #pragma unroll
        for (int p = 0; p < 2; ++p) {
            const int il = half * 2 + p;
            float dx = pb[(i0 + il) * 3 + 0] - pjx;   // i-coords: uniform loads
            float dy = pb[(i0 + il) * 3 + 1] - pjy;
            float dz = pb[(i0 + il) * 3 + 2] - pjz;
            float sq = dx * dx + dy * dy + dz * dz;
            dt[il][j] = (sq > 0.f) ? sqrtf(sq) : 0.f;
        }
    }
    if (t < 64) {   // cnt = sum_j mask[b][j]
        float mv = mask[b * N_ + t] + mask[b * N_ + 64 + t]
                 + mask[b * N_ + 128 + t] + mask[b * N_ + 192 + t];
        #pragma unroll
        for (int off = 32; off >= 1; off >>= 1) mv += __shfl_down(mv, off);
        if (t == 0) cs = mv;
    }

    const int i = t >> 7;             // wave-uniform
    const int c = t & 127;
    const float wd   = We1[256 * H_ + c];
    const float base = P[(size_t)(b * N_ + i0 + i) * H_ + c];
    const float4* __restrict__ Qg = (const float4*)(Q + (size_t)(b * N_) * H_);

    // prefetch chunk 0: 64 j x 128 c = 32 KB; 512 threads x 4 float4
    float4 r0 = Qg[0 * 512 + t];
    float4 r1 = Qg[1 * 512 + t];
    float4 r2 = Qg[2 * 512 + t];
    float4 r3 = Qg[3 * 512 + t];

    float acc = 0.f;
    for (int ch = 0; ch < 4; ++ch) {
        __syncthreads();              // previous chunk's compute done
        ((float4*)arena)[0 * 512 + t] = r0;
        ((float4*)arena)[1 * 512 + t] = r1;
        ((float4*)arena)[2 * 512 + t] = r2;
        ((float4*)arena)[3 * 512 + t] = r3;
        if (ch < 3) {                 // prefetch next chunk during compute
            r0 = Qg[(ch + 1) * 2048 + 0 * 512 + t];
            r1 = Qg[(ch + 1) * 2048 + 1 * 512 + t];
            r2 = Qg[(ch + 1) * 2048 + 2 * 512 + t];
            r3 = Qg[(ch + 1) * 2048 + 3 * 512 + t];
        }
        __syncthreads();              // staging visible
        const int j0 = ch * 64;
        #pragma unroll 4
        for (int jw = 0; jw < 64; jw += 4) {
            float4 d4 = *(const float4*)(&dt[i][j0 + jw]);   // broadcast b128
            #pragma unroll
            for (int u = 0; u < 4; ++u) {
                float q  = arena[(jw + u) * 128 + c];
                float du = (u == 0) ? d4.x : (u == 1) ? d4.y : (u == 2) ? d4.z : d4.w;
                float x  = fmaf(du, wd, base + q);
                float e  = __expf(-x);
                float rr = __builtin_amdgcn_rcpf(1.0f + e);
                acc = fmaf(x, rr, acc);   // masked j: x~-1e30, rr=0 -> +(-0)
            }
        }
    }

    const float inv_cnt = __builtin_amdgcn_rcpf(fmaxf(cs, 1.0f));
    const float mi = mask[b * N_ + i0 + i];
    Sls[i][c] = (mi * inv_cnt) * acc;
    __syncthreads();                  // Sls visible; arena free for pls

    // ---- epilogue: split-K GEMMs (16 ksegs x 8 k) ----
    float (*pls)[4][128] = (float (*)[4][128])arena;
    const int kseg = t >> 5;          // 0..15
    const int c0   = (t & 31) * 4;

    // G1: T = S' @ We2 + mi*be2
    {
        const float* Wb = We2 + (size_t)(kseg * 8) * H_ + c0;
        float4 w[8];
        #pragma unroll
        for (int u = 0; u < 8; ++u) w[u] = *(const float4*)(Wb + u * H_);
        #pragma unroll
        for (int n = 0; n < 4; ++n) {
            float4 a = {0.f, 0.f, 0.f, 0.f};
            #pragma unroll
            for (int u = 0; u < 8; ++u) {
                float v = Sls[n][kseg * 8 + u];
                a.x = fmaf(v, w[u].x, a.x); a.y = fmaf(v, w[u].y, a.y);
                a.z = fmaf(v, w[u].z, a.z); a.w = fmaf(v, w[u].w, a.w);
            }
            *(float4*)(&pls[kseg][n][c0]) = a;
        }
    }
    __syncthreads();
    {
        float s = 0.f;
        #pragma unroll
        for (int seg = 0; seg < 16; ++seg) s += pls[seg][i][c];
        Tls[i][c] = fmaf(mi, be2[c], s);
    }
    __syncthreads();

    // G2: hidden = silu(pre + T @ Wn1[128:])
    {
        const float* Wb = Wn1 + (size_t)(128 + kseg * 8) * H_ + c0;
        float4 w[8];
        #pragma unroll
        for (int u = 0; u < 8; ++u) w[u] = *(const float4*)(Wb + u * H_);
        #pragma unroll
        for (int n = 0; n < 4; ++n) {
            float4 a = {0.f, 0.f, 0.f, 0.f};
            #pragma unroll
            for (int u = 0; u < 8; ++u) {
                float v = Tls[n][kseg * 8 + u];
                a.x = fmaf(v, w[u].x, a.x); a.y = fmaf(v, w[u].y, a.y);
                a.z = fmaf(v, w[u].z, a.z); a.w = fmaf(v, w[u].w, a.w);
            }
            *(float4*)(&pls[kseg][n][c0]) = a;
        }
    }
    __syncthreads();
    {
        float s = 0.f;
        #pragma unroll
        for (int seg = 0; seg < 16; ++seg) s += pls[seg][i][c];
        Sls[i][c] = silu_fast(pre[(size_t)(b * N_ + i0 + i) * H_ + c] + s);
    }
    __syncthreads();

    // G3: out = node + mi * (hidden @ Wn2 + bn2)
    {
        const float* Wb = Wn2 + (size_t)(kseg * 8) * H_ + c0;
        float4 w[8];
        #pragma unroll
        for (int u = 0; u < 8; ++u) w[u] = *(const float4*)(Wb + u * H_);
        #pragma unroll
        for (int n = 0; n < 4; ++n) {
            float4 a = {0.f, 0.f, 0.f, 0.f};
            #pragma unroll
            for (int u = 0; u < 8; ++u) {
                float v = Sls[n][kseg * 8 + u];
                a.x = fmaf(v, w[u].x, a.x); a.y = fmaf(v, w[u].y, a.y);
                a.z = fmaf(v, w[u].z, a.z); a.w = fmaf(v, w[u].w, a.w);
            }
            *(float4*)(&pls[kseg][n][c0]) = a;
        }
    }
    __syncthreads();
    {
        float s = 0.f;
        #pragma unroll
        for (int seg = 0; seg < 16; ++seg) s += pls[seg][i][c];
        const size_t idx = (size_t)(b * N_ + i0 + i) * H_ + c;
        out[idx] = node[idx] + mi * (s + bn2[c]);
    }
}

extern "C" void kernel_launch(void* const* d_in, const int* in_sizes, int n_in,
                              void* d_out, int out_size, void* d_ws, size_t ws_size,
                              hipStream_t stream)
{
    const float* node      = (const float*)d_in[0];
    const float* positions = (const float*)d_in[1];
    const float* mask      = (const float*)d_in[2];
    const float* We1       = (const float*)d_in[3];
    const float* be1       = (const float*)d_in[4];
    const float* We2       = (const float*)d_in[5];
    const float* be2       = (const float*)d_in[6];
    const float* Wn1       = (const float*)d_in[7];
    const float* bn1       = (const float*)d_in[8];
    const float* Wn2       = (const float*)d_in[9];
    const float* bn2       = (const float*)d_in[10];
    float* out = (float*)d_out;

    const size_t SZ = (size_t)NODES_ * H_;     // 1 MB each
    float* P   = (float*)d_ws;
    float* Q   = P + SZ;
    float* pre = Q + SZ;                       // peak ws = 3 MB

    k1  <<<1536, 512, 0, stream>>>(node, We1, be1, Wn1, bn1, mask, P, Q, pre);
    k2bc<<<512,  512, 0, stream>>>(P, Q, We1, positions, mask, pre, node,
                                   We2, be2, Wn1, Wn2, bn2, out);
}